// Round 1
// baseline (29335.284 us; speedup 1.0000x reference)
//
#include <hip/hip_runtime.h>

// ESN leaky reservoir: res_{t+1} = 0.5*res_t + 0.5*tanh(x_t@i2h + res_t@h2h)
// Persistent-kernel design: 256 WGs = 16 column tiles (W=128) x 16 K-slices (Ks=128).
// h2h (fp16) lives in VGPRs (B-fragments, loaded once). Flag-based producer/consumer
// sync, no grid barrier. fp16 MFMA, fp32 accumulate/state.

typedef _Float16 f16x8 __attribute__((ext_vector_type(8)));
typedef float f32x4 __attribute__((ext_vector_type(4)));

#define NB 64      // batch
#define RDIM 2048  // reservoir
#define TT 256     // timesteps
#define IDIM 128   // input dim

// ---------------- setup kernels ----------------

__global__ __launch_bounds__(256) void transpose_f32_to_f16(
    const float* __restrict__ in, _Float16* __restrict__ out, int rows, int cols) {
  // out[c][r] = (f16) in[r][c]; rows, cols multiples of 64
  __shared__ float tile[64][65];
  const int tx = threadIdx.x & 63;
  const int ty = threadIdx.x >> 6;  // 0..3
  const int rbase = blockIdx.y * 64;
  const int cbase = blockIdx.x * 64;
  for (int rr = ty; rr < 64; rr += 4)
    tile[rr][tx] = in[(size_t)(rbase + rr) * cols + cbase + tx];
  __syncthreads();
  for (int rr = ty; rr < 64; rr += 4)
    out[(size_t)(cbase + rr) * rows + rbase + tx] = (_Float16)tile[tx][rr];
}

__global__ __launch_bounds__(256) void convert_f32_f16(
    const float* __restrict__ in, _Float16* __restrict__ out, int n) {
  int i = blockIdx.x * 256 + threadIdx.x;
  int stride = gridDim.x * 256;
  for (; i < n; i += stride) out[i] = (_Float16)in[i];
}

__global__ __launch_bounds__(256) void init_zero(
    unsigned* __restrict__ res_words, unsigned* __restrict__ ctr_words) {
  int i = blockIdx.x * 256 + threadIdx.x;
  if (i < NB * RDIM / 2) res_words[i] = 0;  // res parity-0 buffer (fp16) = 0
  if (i < 64) ctr_words[i] = 0;             // counters
}

// ---------------- persistent ESN kernel ----------------

__device__ __forceinline__ void spin_ge(unsigned* p, unsigned tgt) {
  while (__hip_atomic_load(p, __ATOMIC_ACQUIRE, __HIP_MEMORY_SCOPE_AGENT) < tgt)
    __builtin_amdgcn_s_sleep(1);
}

__global__ __launch_bounds__(256) void esn_persist(
    const _Float16* __restrict__ h2hT,   // [RDIM n][RDIM k]  (= h2h[k][n])
    const _Float16* __restrict__ i2hT,   // [RDIM n][IDIM i]
    const _Float16* __restrict__ x16,    // [NB][TT][IDIM]
    _Float16* __restrict__ resbuf,       // [2][NB][RDIM]
    float* __restrict__ part,            // [2][16 j][16 k][NB][128]
    float* __restrict__ pout,            // [16][640]
    unsigned* __restrict__ ctrs,         // [64]
    const float* __restrict__ out_w,     // [RDIM][10]
    const float* __restrict__ out_b,     // [10]
    float* __restrict__ out)             // [640 + NB*TT*RDIM]
{
  const int bid = blockIdx.x;
  const int j = bid >> 4;   // column tile: cols [128j, 128j+128)
  const int k = bid & 15;   // K slice:   rows [128k, 128k+128)
  const int tid = threadIdx.x;
  const int wave = tid >> 6;
  const int lane = tid & 63;
  const int l15 = lane & 15;
  const int q = lane >> 4;

  unsigned* done_res  = ctrs;        // [16] 16 increments per tile per step
  unsigned* done_part = ctrs + 16;   // [16]
  unsigned* rd_done   = ctrs + 32;   // [16] read-acks of tile outputs
  unsigned* pctr      = ctrs + 48;

  // Preload stationary B fragments: B[k][n] layout for mfma_16x16x32_f16:
  // lane holds B[kbase + kk*32 + q*8 + jj][nabs], jj=0..7 contiguous in h2hT.
  f16x8 bfr[4][2];
  for (int kk = 0; kk < 4; ++kk)
    for (int nt = 0; nt < 2; ++nt) {
      int n_abs = j * 128 + wave * 32 + nt * 16 + l15;
      bfr[kk][nt] = *(const f16x8*)(h2hT + (size_t)n_abs * RDIM + k * 128 + kk * 32 + q * 8);
    }
  f16x8 ib[2];
  if (k < 4) {  // this WG also adds the xin slice i in [32k, 32k+32)
    for (int nt = 0; nt < 2; ++nt) {
      int n_abs = j * 128 + wave * 32 + nt * 16 + l15;
      ib[nt] = *(const f16x8*)(i2hT + (size_t)n_abs * IDIM + k * 32 + q * 8);
    }
  }

  // per-thread state: chunk rows b0,b1 of tile j (batches [4k,4k+4) split over threads)
  const int col = tid & 127;
  const int rl = tid >> 7;  // 0..1
  const int b0 = 4 * k + rl;
  const int b1 = b0 + 2;
  float s0 = 0.f, s1 = 0.f;

  for (int t = 0; t < TT; ++t) {
    const int par = t & 1;
    const int par1 = par ^ 1;

    // 1. wait for my single producer tile (tile k produced cols [128k,128k+128) of S_t)
    if (tid == 0) spin_ge(done_res + k, 16u * (unsigned)t);
    __syncthreads();

    // 2. partial GEMM: S_t[:, 128k:128k+128] @ h2h[128k:128k+128, 128j:128j+128]
    const _Float16* resp = resbuf + par * (NB * RDIM);
    f32x4 acc[4][2] = {};
    for (int kk = 0; kk < 4; ++kk) {
      for (int mt = 0; mt < 4; ++mt) {
        f16x8 a = *(const f16x8*)(resp + (size_t)(mt * 16 + l15) * RDIM + k * 128 + kk * 32 + q * 8);
        acc[mt][0] = __builtin_amdgcn_mfma_f32_16x16x32_f16(a, bfr[kk][0], acc[mt][0], 0, 0, 0);
        acc[mt][1] = __builtin_amdgcn_mfma_f32_16x16x32_f16(a, bfr[kk][1], acc[mt][1], 0, 0, 0);
      }
    }
    if (k < 4) {  // fused xin contribution for input slice
      for (int mt = 0; mt < 4; ++mt) {
        f16x8 a = *(const f16x8*)(x16 + ((size_t)(mt * 16 + l15) * TT + t) * IDIM + k * 32 + q * 8);
        acc[mt][0] = __builtin_amdgcn_mfma_f32_16x16x32_f16(a, ib[0], acc[mt][0], 0, 0, 0);
        acc[mt][1] = __builtin_amdgcn_mfma_f32_16x16x32_f16(a, ib[1], acc[mt][1], 0, 0, 0);
      }
    }

    // 3. write partials (C/D layout: m = mt*16 + q*4 + r, n = wave*32 + nt*16 + l15)
    float* pp = part + ((size_t)(par1 * 16 + j) * 16 + k) * (NB * 128);
    for (int mt = 0; mt < 4; ++mt)
      for (int nt = 0; nt < 2; ++nt)
        for (int r = 0; r < 4; ++r)
          pp[(mt * 16 + q * 4 + r) * 128 + wave * 32 + nt * 16 + l15] = acc[mt][nt][r];
    __threadfence();
    __syncthreads();
    if (tid == 0) {
      // ack my read of tile k's output (loads are ordered before RELEASE atomic)
      __hip_atomic_fetch_add(rd_done + k, 1u, __ATOMIC_RELEASE, __HIP_MEMORY_SCOPE_AGENT);
      __hip_atomic_fetch_add(done_part + j, 1u, __ATOMIC_RELEASE, __HIP_MEMORY_SCOPE_AGENT);
      // wait: all 16 partials of tile j present (RAW), and all step-(t-1) readers of
      // the res buffer we are about to overwrite have acked (WAR)
      spin_ge(done_part + j, 16u * (unsigned)(t + 1));
      spin_ge(rd_done + j, 16u * (unsigned)t);
    }
    __syncthreads();

    // 4. reduce 16 partials, activation, leak, publish
    const float* pb = part + ((size_t)(par1 * 16 + j) * 16) * (NB * 128);
    float a0 = 0.f, a1 = 0.f;
    for (int kk = 0; kk < 16; ++kk) {
      a0 += pb[(size_t)kk * (NB * 128) + b0 * 128 + col];
      a1 += pb[(size_t)kk * (NB * 128) + b1 * 128 + col];
    }
    s0 = 0.5f * s0 + 0.5f * tanhf(a0);
    s1 = 0.5f * s1 + 0.5f * tanhf(a1);
    _Float16* resw = resbuf + par1 * (NB * RDIM);
    resw[(size_t)b0 * RDIM + j * 128 + col] = (_Float16)s0;
    resw[(size_t)b1 * RDIM + j * 128 + col] = (_Float16)s1;
    out[640 + ((size_t)b0 * TT + t) * RDIM + j * 128 + col] = s0;
    out[640 + ((size_t)b1 * TT + t) * RDIM + j * 128 + col] = s1;
    __threadfence();
    __syncthreads();
    if (tid == 0)
      __hip_atomic_fetch_add(done_res + j, 1u, __ATOMIC_RELEASE, __HIP_MEMORY_SCOPE_AGENT);
  }

  // ---------------- final readout: out = S_256 @ out_w + out_b ----------------
  if (j == 0) {
    if (tid == 0) spin_ge(done_res + k, 16u * (unsigned)TT);
    __syncthreads();
    const _Float16* rlast = resbuf;  // parity (256 & 1) = 0
    for (int o = tid; o < 640; o += 256) {
      int b = o / 10, oo = o - 10 * b;
      float a = 0.f;
      for (int r = 0; r < 128; ++r)
        a += (float)rlast[(size_t)b * RDIM + k * 128 + r] * out_w[(size_t)(k * 128 + r) * 10 + oo];
      pout[k * 640 + o] = a;
    }
    __threadfence();
    __syncthreads();
    if (tid == 0)
      __hip_atomic_fetch_add(pctr, 1u, __ATOMIC_RELEASE, __HIP_MEMORY_SCOPE_AGENT);
    if (k == 0) {
      if (tid == 0) spin_ge(pctr, 16u);
      __syncthreads();
      for (int o = tid; o < 640; o += 256) {
        float a = out_b[o % 10];
        for (int kk = 0; kk < 16; ++kk) a += pout[kk * 640 + o];
        out[o] = a;
      }
    }
  }
}

// ---------------- host launcher ----------------

extern "C" void kernel_launch(void* const* d_in, const int* in_sizes, int n_in,
                              void* d_out, int out_size, void* d_ws, size_t ws_size,
                              hipStream_t stream) {
  const float* x     = (const float*)d_in[0];  // (64,256,128)
  const float* i2h_w = (const float*)d_in[1];  // (128,2048)
  const float* h2h   = (const float*)d_in[2];  // (2048,2048)
  const float* out_w = (const float*)d_in[3];  // (2048,10)
  const float* out_b = (const float*)d_in[4];  // (10,)
  float* out = (float*)d_out;

  unsigned char* ws = (unsigned char*)d_ws;
  // ws layout (bytes):
  _Float16* h2hT   = (_Float16*)(ws + 0);             // 8,388,608
  _Float16* i2hT   = (_Float16*)(ws + 8388608);       //   524,288
  _Float16* x16    = (_Float16*)(ws + 8912896);       // 4,194,304
  _Float16* resbuf = (_Float16*)(ws + 13107200);      //   524,288
  float*    part   = (float*)   (ws + 13631488);      // 16,777,216
  float*    pout   = (float*)   (ws + 30408704);      //    40,960
  unsigned* ctrs   = (unsigned*)(ws + 30449664);      //       256
  // total ~30.45 MB

  transpose_f32_to_f16<<<dim3(32, 32), dim3(256), 0, stream>>>(h2h, h2hT, 2048, 2048);
  transpose_f32_to_f16<<<dim3(32, 2), dim3(256), 0, stream>>>(i2h_w, i2hT, 128, 2048);
  convert_f32_f16<<<dim3(512), dim3(256), 0, stream>>>(x, x16, NB * TT * IDIM);
  init_zero<<<dim3(256), dim3(256), 0, stream>>>((unsigned*)resbuf, ctrs);
  esn_persist<<<dim3(256), dim3(256), 0, stream>>>(h2hT, i2hT, x16, resbuf, part, pout,
                                                   ctrs, out_w, out_b, out);
}

// Round 2
// 6475.817 us; speedup vs baseline: 4.5300x; 4.5300x over previous
//
#include <hip/hip_runtime.h>

// ESN leaky reservoir: res_{t+1} = 0.5*res_t + 0.5*tanh(x_t@i2h + res_t@h2h)
// Round 2: 64 WGs x 32 columns, FULL K per WG (wave w holds K in [512w,512w+512)
// as stationary B-fragments in VGPRs, 128 VGPR/lane). Cross-wave reduction in
// LDS. Only cross-WG sync: one barrier counter per step (res is double-buffered).
// No global partials exchange (Round 1's 4 GB/step-chain killer).

typedef _Float16 f16x8 __attribute__((ext_vector_type(8)));
typedef float f32x4 __attribute__((ext_vector_type(4)));

#define NB 64      // batch
#define RDIM 2048  // reservoir
#define TT 256     // timesteps
#define IDIM 128   // input dim
#define NWG 64     // workgroups; each owns 32 columns

// ---------------- setup kernels ----------------

__global__ __launch_bounds__(256) void transpose_f32_to_f16(
    const float* __restrict__ in, _Float16* __restrict__ out, int rows, int cols) {
  // out[c][r] = (f16) in[r][c]; rows, cols multiples of 64
  __shared__ float tile[64][65];
  const int tx = threadIdx.x & 63;
  const int ty = threadIdx.x >> 6;  // 0..3
  const int rbase = blockIdx.y * 64;
  const int cbase = blockIdx.x * 64;
  for (int rr = ty; rr < 64; rr += 4)
    tile[rr][tx] = in[(size_t)(rbase + rr) * cols + cbase + tx];
  __syncthreads();
  for (int rr = ty; rr < 64; rr += 4)
    out[(size_t)(cbase + rr) * rows + rbase + tx] = (_Float16)tile[tx][rr];
}

__global__ __launch_bounds__(256) void convert_f32_f16(
    const float* __restrict__ in, _Float16* __restrict__ out, int n) {
  int i = blockIdx.x * 256 + threadIdx.x;
  int stride = gridDim.x * 256;
  for (; i < n; i += stride) out[i] = (_Float16)in[i];
}

__global__ __launch_bounds__(256) void init_zero(
    unsigned* __restrict__ res_words, unsigned* __restrict__ ctr_words) {
  int i = blockIdx.x * 256 + threadIdx.x;
  if (i < NB * RDIM / 2) res_words[i] = 0;  // res parity-0 buffer (fp16) = 0
  if (i < 64) ctr_words[i] = 0;             // counters
}

// ---------------- persistent ESN kernel ----------------

__device__ __forceinline__ void spin_ge(unsigned* p, unsigned tgt) {
  while (__hip_atomic_load(p, __ATOMIC_ACQUIRE, __HIP_MEMORY_SCOPE_AGENT) < tgt)
    __builtin_amdgcn_s_sleep(1);
}

__device__ __forceinline__ f32x4 MF(f16x8 a, f16x8 b, f32x4 c) {
  return __builtin_amdgcn_mfma_f32_16x16x32_f16(a, b, c, 0, 0, 0);
}

__global__ __launch_bounds__(256, 1) void esn_persist(
    const _Float16* __restrict__ h2hT,   // [RDIM n][RDIM k]  (= h2h[k][n])
    const _Float16* __restrict__ i2hT,   // [RDIM n][IDIM i]
    const _Float16* __restrict__ x16,    // [NB][TT][IDIM]
    _Float16* __restrict__ resbuf,       // [2][NB][RDIM]
    float* __restrict__ pout,            // [16][640]
    unsigned* __restrict__ ctrs,         // [64]: [0]=step barrier, [1]=readout
    const float* __restrict__ out_w,     // [RDIM][10]
    const float* __restrict__ out_b,     // [10]
    float* __restrict__ out)             // [640 + NB*TT*RDIM]
{
  const int g = blockIdx.x;        // column group: cols [32g, 32g+32)
  const int jbase = g * 32;
  const int tid = threadIdx.x;
  const int wave = tid >> 6;       // K slice [512*wave, 512*wave+512)
  const int lane = tid & 63;
  const int l15 = lane & 15;
  const int q = lane >> 4;

  unsigned* step_ctr = ctrs;       // NWG increments per step
  unsigned* pctr     = ctrs + 1;

  // Stationary B fragments: lane holds B[kbase + kt*32 + q*8 + jj][n_abs],
  // jj=0..7 contiguous along k in h2hT[n][k].
  f16x8 bfr[16][2];
  for (int kt = 0; kt < 16; ++kt)
    for (int nt = 0; nt < 2; ++nt) {
      int n_abs = jbase + nt * 16 + l15;
      bfr[kt][nt] = *(const f16x8*)(h2hT + (size_t)n_abs * RDIM + wave * 512 + kt * 32 + q * 8);
    }
  // i2h fragments: wave w covers input slice i in [32w, 32w+32)
  f16x8 ib[2];
  for (int nt = 0; nt < 2; ++nt) {
    int n_abs = jbase + nt * 16 + l15;
    ib[nt] = *(const f16x8*)(i2hT + (size_t)n_abs * IDIM + wave * 32 + q * 8);
  }

  // LDS partial buffer: [wave][m 64][col 32], padded 33 to kill 4-way bank conflict
  __shared__ float pl[4][64][33];

  // per-thread state: col = tid&31, rows m = (tid>>5)*8 + r
  const int col = tid & 31;
  const int mrow = (tid >> 5) * 8;
  float s[8];
  for (int r = 0; r < 8; ++r) s[r] = 0.f;

  for (int t = 0; t < TT; ++t) {
    const int par = t & 1;
    const int par1 = par ^ 1;

    // 1. barrier: all res_t writes visible
    if (tid == 0) spin_ge(step_ctr, (unsigned)NWG * (unsigned)t);
    __syncthreads();

    // 2. full-K partial GEMM for this wave's K slice
    const _Float16* resp = resbuf + par * (NB * RDIM);
    f32x4 acc[4][2] = {};
    for (int kt = 0; kt < 16; ++kt) {
      for (int mt = 0; mt < 4; ++mt) {
        f16x8 a = *(const f16x8*)(resp + (size_t)(mt * 16 + l15) * RDIM + wave * 512 + kt * 32 + q * 8);
        acc[mt][0] = MF(a, bfr[kt][0], acc[mt][0]);
        acc[mt][1] = MF(a, bfr[kt][1], acc[mt][1]);
      }
    }
    // fused xin: wave w adds input slice [32w, 32w+32)
    for (int mt = 0; mt < 4; ++mt) {
      f16x8 a = *(const f16x8*)(x16 + ((size_t)(mt * 16 + l15) * TT + t) * IDIM + wave * 32 + q * 8);
      acc[mt][0] = MF(a, ib[0], acc[mt][0]);
      acc[mt][1] = MF(a, ib[1], acc[mt][1]);
    }

    // 3. stash partials in LDS (C/D layout: m = mt*16 + q*4 + r, n = nt*16 + l15)
    for (int mt = 0; mt < 4; ++mt)
      for (int nt = 0; nt < 2; ++nt)
        for (int r = 0; r < 4; ++r)
          pl[wave][mt * 16 + q * 4 + r][nt * 16 + l15] = acc[mt][nt][r];
    __syncthreads();

    // 4. 4-way reduce, activation, leak, publish
    _Float16* resw = resbuf + par1 * (NB * RDIM);
    for (int r = 0; r < 8; ++r) {
      int m = mrow + r;
      float a = pl[0][m][col] + pl[1][m][col] + pl[2][m][col] + pl[3][m][col];
      s[r] = 0.5f * s[r] + 0.5f * tanhf(a);
      resw[(size_t)m * RDIM + jbase + col] = (_Float16)s[r];
      out[640 + ((size_t)m * TT + t) * RDIM + jbase + col] = s[r];
    }
    __threadfence();
    __syncthreads();
    if (tid == 0)
      __hip_atomic_fetch_add(step_ctr, 1u, __ATOMIC_RELEASE, __HIP_MEMORY_SCOPE_AGENT);
  }

  // ---------------- final readout: out = S_256 @ out_w + out_b ----------------
  if (g < 16) {
    if (tid == 0) spin_ge(step_ctr, (unsigned)NWG * (unsigned)TT);
    __syncthreads();
    const _Float16* rlast = resbuf;  // parity (256 & 1) = 0
    for (int o = tid; o < 640; o += 256) {
      int b = o / 10, oo = o - 10 * b;
      float a = 0.f;
      for (int r = 0; r < 128; ++r)
        a += (float)rlast[(size_t)b * RDIM + g * 128 + r] * out_w[(size_t)(g * 128 + r) * 10 + oo];
      pout[g * 640 + o] = a;
    }
    __threadfence();
    __syncthreads();
    if (tid == 0)
      __hip_atomic_fetch_add(pctr, 1u, __ATOMIC_RELEASE, __HIP_MEMORY_SCOPE_AGENT);
    if (g == 0) {
      if (tid == 0) spin_ge(pctr, 16u);
      __syncthreads();
      for (int o = tid; o < 640; o += 256) {
        float a = out_b[o % 10];
        for (int kk = 0; kk < 16; ++kk) a += pout[kk * 640 + o];
        out[o] = a;
      }
    }
  }
}

// ---------------- host launcher ----------------

extern "C" void kernel_launch(void* const* d_in, const int* in_sizes, int n_in,
                              void* d_out, int out_size, void* d_ws, size_t ws_size,
                              hipStream_t stream) {
  const float* x     = (const float*)d_in[0];  // (64,256,128)
  const float* i2h_w = (const float*)d_in[1];  // (128,2048)
  const float* h2h   = (const float*)d_in[2];  // (2048,2048)
  const float* out_w = (const float*)d_in[3];  // (2048,10)
  const float* out_b = (const float*)d_in[4];  // (10,)
  float* out = (float*)d_out;

  unsigned char* ws = (unsigned char*)d_ws;
  // ws layout (bytes):
  _Float16* h2hT   = (_Float16*)(ws + 0);             // 8,388,608
  _Float16* i2hT   = (_Float16*)(ws + 8388608);       //   524,288
  _Float16* x16    = (_Float16*)(ws + 8912896);       // 4,194,304
  _Float16* resbuf = (_Float16*)(ws + 13107200);      //   524,288
  float*    pout   = (float*)   (ws + 13631488);      //    40,960
  unsigned* ctrs   = (unsigned*)(ws + 13672448);      //       256
  // total ~13.7 MB

  transpose_f32_to_f16<<<dim3(32, 32), dim3(256), 0, stream>>>(h2h, h2hT, 2048, 2048);
  transpose_f32_to_f16<<<dim3(32, 2), dim3(256), 0, stream>>>(i2h_w, i2hT, 128, 2048);
  convert_f32_f16<<<dim3(512), dim3(256), 0, stream>>>(x, x16, NB * TT * IDIM);
  init_zero<<<dim3(256), dim3(256), 0, stream>>>((unsigned*)resbuf, ctrs);
  esn_persist<<<dim3(NWG), dim3(256), 0, stream>>>(h2hT, i2hT, x16, resbuf, pout,
                                                   ctrs, out_w, out_b, out);
}

// Round 4
// 5487.062 us; speedup vs baseline: 5.3463x; 1.1802x over previous
//
#include <hip/hip_runtime.h>

// ESN leaky reservoir: res_{t+1} = 0.5*res_t + 0.5*tanh(x_t@i2h + res_t@h2h)
// Round 4 (= Round 3 + compile fix): 64 WGs x 32 cols, full K in VGPRs,
// LDS reduce; fence-free cross-WG exchange:
//  - res + counters via RELAXED SYSTEM-scope atomics -> sc0/sc1 write-through
//    stores / cache-bypassing loads (coherent at L3). No __threadfence / wbl2
//    in the step loop (__syncthreads drains vmcnt -> stores visible).
//  - arrival counter split 8 ways (128B-spaced lines): 8 serialized RMW max.
//  - hiddens via nontemporal ext-vector stores (fix: f32x4, not HIP float4).

typedef _Float16 f16x8 __attribute__((ext_vector_type(8)));
typedef float f32x4 __attribute__((ext_vector_type(4)));

#define NB 64      // batch
#define RDIM 2048  // reservoir
#define TT 256     // timesteps
#define IDIM 128   // input dim
#define NWG 64     // workgroups; each owns 32 columns

// ---------------- setup kernels ----------------

__global__ __launch_bounds__(256) void transpose_f32_to_f16(
    const float* __restrict__ in, _Float16* __restrict__ out, int rows, int cols) {
  __shared__ float tile[64][65];
  const int tx = threadIdx.x & 63;
  const int ty = threadIdx.x >> 6;
  const int rbase = blockIdx.y * 64;
  const int cbase = blockIdx.x * 64;
  for (int rr = ty; rr < 64; rr += 4)
    tile[rr][tx] = in[(size_t)(rbase + rr) * cols + cbase + tx];
  __syncthreads();
  for (int rr = ty; rr < 64; rr += 4)
    out[(size_t)(cbase + rr) * rows + rbase + tx] = (_Float16)tile[tx][rr];
}

__global__ __launch_bounds__(256) void convert_f32_f16(
    const float* __restrict__ in, _Float16* __restrict__ out, int n) {
  int i = blockIdx.x * 256 + threadIdx.x;
  int stride = gridDim.x * 256;
  for (; i < n; i += stride) out[i] = (_Float16)in[i];
}

__global__ __launch_bounds__(256) void init_zero(
    unsigned* __restrict__ res_words, unsigned* __restrict__ ctr_words) {
  int i = blockIdx.x * 256 + threadIdx.x;
  if (i < NB * RDIM / 2) res_words[i] = 0;  // res parity-0 buffer (fp16) = 0
  if (i < 512) ctr_words[i] = 0;            // counters
}

// ---------------- coherent access helpers (sc0/sc1, no fences) ----------------

__device__ __forceinline__ f16x8 load_res16(const _Float16* p) {
  union { unsigned long long u[2]; f16x8 v; } r;
  const unsigned long long* q = (const unsigned long long*)p;
  r.u[0] = __hip_atomic_load(q, __ATOMIC_RELAXED, __HIP_MEMORY_SCOPE_SYSTEM);
  r.u[1] = __hip_atomic_load(q + 1, __ATOMIC_RELAXED, __HIP_MEMORY_SCOPE_SYSTEM);
  return r.v;
}

__device__ __forceinline__ void store_res16(_Float16* p, f16x8 v) {
  union { f16x8 v; unsigned long long u[2]; } r;
  r.v = v;
  unsigned long long* q = (unsigned long long*)p;
  __hip_atomic_store(q, r.u[0], __ATOMIC_RELAXED, __HIP_MEMORY_SCOPE_SYSTEM);
  __hip_atomic_store(q + 1, r.u[1], __ATOMIC_RELAXED, __HIP_MEMORY_SCOPE_SYSTEM);
}

// arrival counters: 8 slots, 128B apart
__device__ __forceinline__ void arrive(unsigned* ctrs, int g) {
  __hip_atomic_fetch_add(&ctrs[(g & 7) * 32], 1u, __ATOMIC_RELAXED,
                         __HIP_MEMORY_SCOPE_SYSTEM);
}

__device__ __forceinline__ void wait_sum(unsigned* ctrs, unsigned tgt) {
  for (;;) {
    unsigned s = 0;
    for (int i = 0; i < 8; ++i)
      s += __hip_atomic_load(&ctrs[i * 32], __ATOMIC_RELAXED, __HIP_MEMORY_SCOPE_SYSTEM);
    if (s >= tgt) return;
    __builtin_amdgcn_s_sleep(1);
  }
}

__device__ __forceinline__ f32x4 MF(f16x8 a, f16x8 b, f32x4 c) {
  return __builtin_amdgcn_mfma_f32_16x16x32_f16(a, b, c, 0, 0, 0);
}

// ---------------- persistent ESN kernel ----------------

__global__ __launch_bounds__(256, 1) void esn_persist(
    const _Float16* __restrict__ h2hT,   // [RDIM n][RDIM k]  (= h2h[k][n])
    const _Float16* __restrict__ i2hT,   // [RDIM n][IDIM i]
    const _Float16* __restrict__ x16,    // [NB][TT][IDIM]
    _Float16* __restrict__ resbuf,       // [2][NB][RDIM]
    float* __restrict__ pout,            // [16][640]
    unsigned* __restrict__ ctrs,         // [512]: [0..255] step slots, [256] readout
    const float* __restrict__ out_w,     // [RDIM][10]
    const float* __restrict__ out_b,     // [10]
    float* __restrict__ out)             // [640 + NB*TT*RDIM]
{
  const int g = blockIdx.x;        // column group: cols [32g, 32g+32)
  const int jbase = g * 32;
  const int tid = threadIdx.x;
  const int wave = tid >> 6;       // K slice [512*wave, 512*wave+512)
  const int lane = tid & 63;
  const int l15 = lane & 15;
  const int q = lane >> 4;

  // Stationary B fragments: lane holds B[kbase + kt*32 + q*8 + jj][n_abs]
  f16x8 bfr[16][2];
  for (int kt = 0; kt < 16; ++kt)
    for (int nt = 0; nt < 2; ++nt) {
      int n_abs = jbase + nt * 16 + l15;
      bfr[kt][nt] = *(const f16x8*)(h2hT + (size_t)n_abs * RDIM + wave * 512 + kt * 32 + q * 8);
    }
  f16x8 ib[2];
  for (int nt = 0; nt < 2; ++nt) {
    int n_abs = jbase + nt * 16 + l15;
    ib[nt] = *(const f16x8*)(i2hT + (size_t)n_abs * IDIM + wave * 32 + q * 8);
  }

  // LDS partial buffer: [wave][m 64][col 32] padded to 33
  __shared__ float pl[4][64][33];

  // reduce mapping: thread owns row m = tid>>2, cols [c8, c8+8)
  const int m = tid >> 2;
  const int c8 = (tid & 3) * 8;
  float s[8];
  for (int r = 0; r < 8; ++r) s[r] = 0.f;

  for (int t = 0; t < TT; ++t) {
    const int par = t & 1;
    const int par1 = par ^ 1;

    // prefetch x fragments (independent of barrier)
    f16x8 ax[4];
    for (int mt = 0; mt < 4; ++mt)
      ax[mt] = *(const f16x8*)(x16 + ((size_t)(mt * 16 + l15) * TT + t) * IDIM + wave * 32 + q * 8);

    // 1. barrier: everyone finished step t-1 (res_t fully published)
    if (tid == 0) wait_sum(ctrs, (unsigned)NWG * (unsigned)t);
    __syncthreads();

    // 2. full-K partial GEMM for this wave's K slice (res via sc0/sc1 loads)
    const _Float16* resp = resbuf + par * (NB * RDIM);
    f32x4 acc[4][2] = {};
    for (int kt = 0; kt < 16; ++kt) {
      for (int mt = 0; mt < 4; ++mt) {
        f16x8 a = load_res16(resp + (size_t)(mt * 16 + l15) * RDIM + wave * 512 + kt * 32 + q * 8);
        acc[mt][0] = MF(a, bfr[kt][0], acc[mt][0]);
        acc[mt][1] = MF(a, bfr[kt][1], acc[mt][1]);
      }
    }
    for (int mt = 0; mt < 4; ++mt) {
      acc[mt][0] = MF(ax[mt], ib[0], acc[mt][0]);
      acc[mt][1] = MF(ax[mt], ib[1], acc[mt][1]);
    }

    // 3. stash partials in LDS (C/D layout: m = mt*16 + q*4 + r, n = nt*16 + l15)
    for (int mt = 0; mt < 4; ++mt)
      for (int nt = 0; nt < 2; ++nt)
        for (int r = 0; r < 4; ++r)
          pl[wave][mt * 16 + q * 4 + r][nt * 16 + l15] = acc[mt][nt][r];
    __syncthreads();

    // 4. 4-way reduce, activation, leak, publish
    _Float16* resw = resbuf + par1 * (NB * RDIM);
    f16x8 frag;
    f32x4 lo, hi;
    for (int r = 0; r < 8; ++r) {
      float a = pl[0][m][c8 + r] + pl[1][m][c8 + r] + pl[2][m][c8 + r] + pl[3][m][c8 + r];
      s[r] = 0.5f * s[r] + 0.5f * tanhf(a);
      frag[r] = (_Float16)s[r];
    }
    lo[0] = s[0]; lo[1] = s[1]; lo[2] = s[2]; lo[3] = s[3];
    hi[0] = s[4]; hi[1] = s[5]; hi[2] = s[6]; hi[3] = s[7];
    store_res16(resw + (size_t)m * RDIM + jbase + c8, frag);
    float* hid = out + 640 + ((size_t)m * TT + t) * RDIM + jbase + c8;
    __builtin_nontemporal_store(lo, (f32x4*)hid);
    __builtin_nontemporal_store(hi, (f32x4*)(hid + 4));
    __syncthreads();  // waits vmcnt(0) per wave -> all sc-stores globally visible
    if (tid == 0) arrive(ctrs, g);
  }

  // ---------------- final readout: out = S_256 @ out_w + out_b ----------------
  if (g < 16) {
    if (tid == 0) wait_sum(ctrs, (unsigned)NWG * (unsigned)TT);
    __syncthreads();
    const _Float16* rlast = resbuf;  // parity (256 & 1) = 0
    for (int o = tid; o < 640; o += 256) {
      int b = o / 10, oo = o - 10 * b;
      float a = 0.f;
      const unsigned* rp = (const unsigned*)(rlast + (size_t)b * RDIM + g * 128);
      for (int r2 = 0; r2 < 64; ++r2) {
        union { unsigned u; _Float16 h[2]; } cv;
        cv.u = __hip_atomic_load(rp + r2, __ATOMIC_RELAXED, __HIP_MEMORY_SCOPE_SYSTEM);
        a += (float)cv.h[0] * out_w[(size_t)(g * 128 + 2 * r2) * 10 + oo];
        a += (float)cv.h[1] * out_w[(size_t)(g * 128 + 2 * r2 + 1) * 10 + oo];
      }
      __hip_atomic_store(&pout[g * 640 + o], a, __ATOMIC_RELAXED, __HIP_MEMORY_SCOPE_SYSTEM);
    }
    __syncthreads();
    if (tid == 0)
      __hip_atomic_fetch_add(&ctrs[256], 1u, __ATOMIC_RELAXED, __HIP_MEMORY_SCOPE_SYSTEM);
    if (g == 0) {
      if (tid == 0) {
        while (__hip_atomic_load(&ctrs[256], __ATOMIC_RELAXED, __HIP_MEMORY_SCOPE_SYSTEM) < 16u)
          __builtin_amdgcn_s_sleep(1);
      }
      __syncthreads();
      for (int o = tid; o < 640; o += 256) {
        float a = out_b[o % 10];
        for (int kk = 0; kk < 16; ++kk)
          a += __hip_atomic_load(&pout[kk * 640 + o], __ATOMIC_RELAXED, __HIP_MEMORY_SCOPE_SYSTEM);
        out[o] = a;
      }
    }
  }
}

// ---------------- host launcher ----------------

extern "C" void kernel_launch(void* const* d_in, const int* in_sizes, int n_in,
                              void* d_out, int out_size, void* d_ws, size_t ws_size,
                              hipStream_t stream) {
  const float* x     = (const float*)d_in[0];  // (64,256,128)
  const float* i2h_w = (const float*)d_in[1];  // (128,2048)
  const float* h2h   = (const float*)d_in[2];  // (2048,2048)
  const float* out_w = (const float*)d_in[3];  // (2048,10)
  const float* out_b = (const float*)d_in[4];  // (10,)
  float* out = (float*)d_out;

  unsigned char* ws = (unsigned char*)d_ws;
  _Float16* h2hT   = (_Float16*)(ws + 0);             // 8,388,608
  _Float16* i2hT   = (_Float16*)(ws + 8388608);       //   524,288
  _Float16* x16    = (_Float16*)(ws + 8912896);       // 4,194,304
  _Float16* resbuf = (_Float16*)(ws + 13107200);      //   524,288
  float*    pout   = (float*)   (ws + 13631488);      //    40,960
  unsigned* ctrs   = (unsigned*)(ws + 13672448);      //     4,096
  // total ~13.7 MB

  transpose_f32_to_f16<<<dim3(32, 32), dim3(256), 0, stream>>>(h2h, h2hT, 2048, 2048);
  transpose_f32_to_f16<<<dim3(32, 2), dim3(256), 0, stream>>>(i2h_w, i2hT, 128, 2048);
  convert_f32_f16<<<dim3(512), dim3(256), 0, stream>>>(x, x16, NB * TT * IDIM);
  init_zero<<<dim3(256), dim3(256), 0, stream>>>((unsigned*)resbuf, ctrs);
  esn_persist<<<dim3(NWG), dim3(256), 0, stream>>>(h2hT, i2hT, x16, resbuf, pout,
                                                   ctrs, out_w, out_b, out);
}